// Round 2
// baseline (884.318 us; speedup 1.0000x reference)
//
#include <hip/hip_runtime.h>

#define POP   128
#define BATCH 256
#define DIN   1024
#define DOUT  1024

#define BM 128
#define BN 128
#define BK 32
#define NKT (DIN / BK)
#define LDS_K (BK + 8)   // bf16 elems; +8 pad: 80B row stride -> free 2-way alias, 16B aligned

typedef __attribute__((ext_vector_type(8))) short  short8v;
typedef __attribute__((ext_vector_type(4))) short  short4v;
typedef __attribute__((ext_vector_type(4))) float  float4v;

// fp32 -> bf16 round-to-nearest-even (inputs are finite Gaussians; no NaN path)
static __device__ __forceinline__ short f2bf(float f) {
    unsigned u = __builtin_bit_cast(unsigned, f);
    u += 0x7fffu + ((u >> 16) & 1u);
    return (short)(u >> 16);
}

// issue 8 float4 global loads (4 A rows + 4 B rows) for K-tile starting at k0
static __device__ __forceinline__ void issue_loads(const float* __restrict__ Ag,
                                                   const float* __restrict__ Bg,
                                                   int k0,
                                                   float4v (&av)[4], float4v (&bv)[4]) {
    #pragma unroll
    for (int pass = 0; pass < 4; ++pass) {
        av[pass] = *(const float4v*)(Ag + (size_t)(pass * 32) * (POP * DIN) + k0);
        bv[pass] = *(const float4v*)(Bg + (size_t)(pass * 32) * DIN + k0);
    }
}

// convert the landed stage to bf16 and publish into the given LDS buffers
static __device__ __forceinline__ void convert_store(short* Asb, short* Bsb,
                                                     int srow, int scol,
                                                     const float4v (&av)[4], const float4v (&bv)[4]) {
    #pragma unroll
    for (int pass = 0; pass < 4; ++pass) {
        short4v a4, b4;
        #pragma unroll
        for (int e = 0; e < 4; ++e) {
            a4[e] = f2bf(av[pass][e]);
            b4[e] = f2bf(bv[pass][e]);
        }
        *(short4v*)&Asb[(pass * 32 + srow) * LDS_K + scol] = a4;
        *(short4v*)&Bsb[(pass * 32 + srow) * LDS_K + scol] = b4;
    }
}

// fragments: A[m = lane&15][k = quad*8+j], B mirrors with n = lane&15
// af read per-i to keep peak register liveness under the 168-VGPR cap
static __device__ __forceinline__ void compute_tile(const short* Asb, const short* Bsb,
                                                    int wm, int wn, int lane15, int quad,
                                                    float4v (&acc)[4][4]) {
    short8v bfr[4];
    #pragma unroll
    for (int j = 0; j < 4; ++j)
        bfr[j] = *(const short8v*)&Bsb[(wn * 64 + j * 16 + lane15) * LDS_K + quad * 8];
    #pragma unroll
    for (int i = 0; i < 4; ++i) {
        short8v afr = *(const short8v*)&Asb[(wm * 64 + i * 16 + lane15) * LDS_K + quad * 8];
        #pragma unroll
        for (int j = 0; j < 4; ++j)
            acc[i][j] = __builtin_amdgcn_mfma_f32_16x16x32_bf16(afr, bfr[j], acc[i][j], 0, 0, 0);
    }
}

__global__ __launch_bounds__(256, 3)
void pop_linear_kernel(const float* __restrict__ x,
                       const float* __restrict__ w,
                       const float* __restrict__ bias,
                       float* __restrict__ out) {
    // double-buffered bf16 tiles: 2 * (128*40 + 128*40) * 2B = 40 KB -> 4 blocks/CU by LDS
    __shared__ short As[2][BM * LDS_K];
    __shared__ short Bs[2][BN * LDS_K];

    const int bid = blockIdx.x;
    // p slow, m_tile middle (stride 8 -> same XCD pair shares W tile), n_tile fast
    const int p      = bid >> 4;
    const int m_tile = (bid >> 3) & 1;
    const int n_tile = bid & 7;

    const int tid    = threadIdx.x;
    const int lane   = tid & 63;
    const int wave   = tid >> 6;   // 0..3
    const int wm     = wave >> 1;  // 0..1  (row half)
    const int wn     = wave & 1;   // 0..1  (col half)
    const int lane15 = lane & 15;
    const int quad   = lane >> 4;  // 0..3

    const int m_base = m_tile * BM;
    const int n_base = n_tile * BN;

    // staging: 256 threads load 128 rows x 32 k-cols (float4 each), 4 passes
    const int srow = tid >> 3;        // 0..31
    const int scol = (tid & 7) * 4;   // 0,4,...,28

    const float* Ag = x + (size_t)(m_base + srow) * (POP * DIN) + (size_t)p * DIN + scol;
    const float* Bg = w + (size_t)p * ((size_t)DOUT * DIN) + (size_t)(n_base + srow) * DIN + scol;

    float4v acc[4][4];
    #pragma unroll
    for (int i = 0; i < 4; ++i)
        #pragma unroll
        for (int j = 0; j < 4; ++j)
            acc[i][j] = (float4v){0.f, 0.f, 0.f, 0.f};

    // two named register stages (static indexing only -- rule #20)
    float4v avA[4], bvA[4], avB[4], bvB[4];

    // ---- prologue: tile0 -> stage A -> buf0; tile1 -> stage B (in flight) ----
    issue_loads(Ag, Bg, 0, avA, bvA);
    convert_store(&As[0][0], &Bs[0][0], srow, scol, avA, bvA);  // waits stage A
    issue_loads(Ag, Bg, BK, avB, bvB);
    __syncthreads();

    // ---- main loop: depth-2 pipeline, one barrier per K-step ----
    // step kt: issue loads(kt+2) [land during step kt AND kt+1],
    //          compute buf[kt&1], convert stage holding tile kt+1 -> buf[kt&1 ^ 1].
    #pragma unroll 1
    for (int kt2 = 0; kt2 < NKT - 2; kt2 += 2) {
        // even step: kt = kt2, cur = 0
        issue_loads(Ag, Bg, (kt2 + 2) * BK, avA, bvA);          // stage A free (consumed last odd step)
        compute_tile(&As[0][0], &Bs[0][0], wm, wn, lane15, quad, acc);
        convert_store(&As[1][0], &Bs[1][0], srow, scol, avB, bvB);  // tile kt2+1, ~1 iter of flight
        __syncthreads();

        // odd step: kt = kt2+1, cur = 1
        issue_loads(Ag, Bg, (kt2 + 3) * BK, avB, bvB);
        compute_tile(&As[1][0], &Bs[1][0], wm, wn, lane15, quad, acc);
        convert_store(&As[0][0], &Bs[0][0], srow, scol, avA, bvA);  // tile kt2+2
        __syncthreads();
    }

    // ---- tail: kt = NKT-2 (cur=0) then kt = NKT-1 (cur=1), no more issues ----
    compute_tile(&As[0][0], &Bs[0][0], wm, wn, lane15, quad, acc);
    convert_store(&As[1][0], &Bs[1][0], srow, scol, avB, bvB);      // tile NKT-1
    __syncthreads();
    compute_tile(&As[1][0], &Bs[1][0], wm, wn, lane15, quad, acc);

    // epilogue: C/D layout m = quad*4 + reg, n = lane&15
    const float* bp = bias + (size_t)p * DOUT;
    float bj[4];
    #pragma unroll
    for (int j = 0; j < 4; ++j)
        bj[j] = bp[n_base + wn * 64 + j * 16 + lane15];

    #pragma unroll
    for (int i = 0; i < 4; ++i) {
        #pragma unroll
        for (int r = 0; r < 4; ++r) {
            const int m = m_base + wm * 64 + i * 16 + quad * 4 + r;
            float* orow = out + (size_t)m * (POP * DOUT) + (size_t)p * DOUT;
            #pragma unroll
            for (int j = 0; j < 4; ++j) {
                const int n = n_base + wn * 64 + j * 16 + lane15;
                orow[n] = acc[i][j][r] + bj[j];
            }
        }
    }
}

extern "C" void kernel_launch(void* const* d_in, const int* in_sizes, int n_in,
                              void* d_out, int out_size, void* d_ws, size_t ws_size,
                              hipStream_t stream) {
    const float* x    = (const float*)d_in[0];
    const float* w    = (const float*)d_in[1];
    const float* bias = (const float*)d_in[2];
    float* out        = (float*)d_out;

    const int grid = POP * (BATCH / BM) * (DOUT / BN);  // 128 * 2 * 8 = 2048
    pop_linear_kernel<<<grid, 256, 0, stream>>>(x, w, bias, out);
}

// Round 3
// 878.646 us; speedup vs baseline: 1.0065x; 1.0065x over previous
//
#include <hip/hip_runtime.h>

#define POP   128
#define BATCH 256
#define DIN   1024
#define DOUT  1024

#define BM 128
#define BN 128
#define BK 32
#define NKT (DIN / BK)
#define LDS_K (BK + 8)   // bf16 elems; +8 pad: 80B row stride -> free 2-way alias, 16B aligned

typedef __attribute__((ext_vector_type(8))) short  short8v;
typedef __attribute__((ext_vector_type(4))) short  short4v;
typedef __attribute__((ext_vector_type(4))) float  float4v;

// fp32 -> bf16 round-to-nearest-even (inputs are finite Gaussians; no NaN path)
static __device__ __forceinline__ short f2bf(float f) {
    unsigned u = __builtin_bit_cast(unsigned, f);
    u += 0x7fffu + ((u >> 16) & 1u);
    return (short)(u >> 16);
}

// LDS-only barrier: drains ds ops (lgkmcnt) but deliberately NOT vmcnt, so the
// depth-2 register prefetch stays in flight across the barrier. __syncthreads()
// would emit s_waitcnt vmcnt(0) and kill the pipeline (the m97-ceiling drain).
// Fused into one asm so the memory clobber pins LDS ops on both sides.
// Safe here: no global stores in the loop; global loads target private VGPRs
// (compiler still inserts exact vmcnt(N) waits for their register uses).
static __device__ __forceinline__ void lds_barrier() {
    asm volatile("s_waitcnt lgkmcnt(0)\n\ts_barrier" ::: "memory");
}

// issue 8 float4 global loads (4 A rows + 4 B rows) for K-tile starting at k0
static __device__ __forceinline__ void issue_loads(const float* __restrict__ Ag,
                                                   const float* __restrict__ Bg,
                                                   int k0,
                                                   float4v (&av)[4], float4v (&bv)[4]) {
    #pragma unroll
    for (int pass = 0; pass < 4; ++pass) {
        av[pass] = *(const float4v*)(Ag + (size_t)(pass * 32) * (POP * DIN) + k0);
        bv[pass] = *(const float4v*)(Bg + (size_t)(pass * 32) * DIN + k0);
    }
}

// convert the landed stage to bf16 and publish into the given LDS buffers
static __device__ __forceinline__ void convert_store(short* Asb, short* Bsb,
                                                     int srow, int scol,
                                                     const float4v (&av)[4], const float4v (&bv)[4]) {
    #pragma unroll
    for (int pass = 0; pass < 4; ++pass) {
        short4v a4, b4;
        #pragma unroll
        for (int e = 0; e < 4; ++e) {
            a4[e] = f2bf(av[pass][e]);
            b4[e] = f2bf(bv[pass][e]);
        }
        *(short4v*)&Asb[(pass * 32 + srow) * LDS_K + scol] = a4;
        *(short4v*)&Bsb[(pass * 32 + srow) * LDS_K + scol] = b4;
    }
}

// fragments: A[m = lane&15][k = quad*8+j], B mirrors with n = lane&15
// af read per-i to keep peak register liveness under the 168-VGPR cap
static __device__ __forceinline__ void compute_tile(const short* Asb, const short* Bsb,
                                                    int wm, int wn, int lane15, int quad,
                                                    float4v (&acc)[4][4]) {
    short8v bfr[4];
    #pragma unroll
    for (int j = 0; j < 4; ++j)
        bfr[j] = *(const short8v*)&Bsb[(wn * 64 + j * 16 + lane15) * LDS_K + quad * 8];
    #pragma unroll
    for (int i = 0; i < 4; ++i) {
        short8v afr = *(const short8v*)&Asb[(wm * 64 + i * 16 + lane15) * LDS_K + quad * 8];
        #pragma unroll
        for (int j = 0; j < 4; ++j)
            acc[i][j] = __builtin_amdgcn_mfma_f32_16x16x32_bf16(afr, bfr[j], acc[i][j], 0, 0, 0);
    }
}

__global__ __launch_bounds__(256, 3)
void pop_linear_kernel(const float* __restrict__ x,
                       const float* __restrict__ w,
                       const float* __restrict__ bias,
                       float* __restrict__ out) {
    // double-buffered bf16 tiles: 2 * (128*40 + 128*40) * 2B = 40 KB
    __shared__ short As[2][BM * LDS_K];
    __shared__ short Bs[2][BN * LDS_K];

    const int bid = blockIdx.x;
    // p slow, m_tile middle (stride 8 -> same XCD pair shares W tile), n_tile fast
    const int p      = bid >> 4;
    const int m_tile = (bid >> 3) & 1;
    const int n_tile = bid & 7;

    const int tid    = threadIdx.x;
    const int lane   = tid & 63;
    const int wave   = tid >> 6;   // 0..3
    const int wm     = wave >> 1;  // 0..1  (row half)
    const int wn     = wave & 1;   // 0..1  (col half)
    const int lane15 = lane & 15;
    const int quad   = lane >> 4;  // 0..3

    const int m_base = m_tile * BM;
    const int n_base = n_tile * BN;

    // staging: 256 threads load 128 rows x 32 k-cols (float4 each), 4 passes
    const int srow = tid >> 3;        // 0..31
    const int scol = (tid & 7) * 4;   // 0,4,...,28

    const float* Ag = x + (size_t)(m_base + srow) * (POP * DIN) + (size_t)p * DIN + scol;
    const float* Bg = w + (size_t)p * ((size_t)DOUT * DIN) + (size_t)(n_base + srow) * DIN + scol;

    float4v acc[4][4];
    #pragma unroll
    for (int i = 0; i < 4; ++i)
        #pragma unroll
        for (int j = 0; j < 4; ++j)
            acc[i][j] = (float4v){0.f, 0.f, 0.f, 0.f};

    // two named register stages (static indexing only -- rule #20)
    float4v avA[4], bvA[4], avB[4], bvB[4];

    // ---- prologue: tile0 -> stage A -> buf0; tile1 -> stage B (in flight) ----
    issue_loads(Ag, Bg, 0, avA, bvA);
    convert_store(&As[0][0], &Bs[0][0], srow, scol, avA, bvA);  // waits stage A
    issue_loads(Ag, Bg, BK, avB, bvB);
    lds_barrier();

    // ---- main loop: depth-2 pipeline, one LDS-only barrier per K-step ----
    // step kt: issue loads(kt+2) [stay in flight ACROSS the barrier],
    //          compute buf[kt&1], convert stage holding tile kt+1 -> buf[kt&1 ^ 1].
    #pragma unroll 1
    for (int kt2 = 0; kt2 < NKT - 2; kt2 += 2) {
        // even step: kt = kt2, cur = 0
        issue_loads(Ag, Bg, (kt2 + 2) * BK, avA, bvA);          // stage A free (consumed last odd step)
        compute_tile(&As[0][0], &Bs[0][0], wm, wn, lane15, quad, acc);
        convert_store(&As[1][0], &Bs[1][0], srow, scol, avB, bvB);  // tile kt2+1
        lds_barrier();

        // odd step: kt = kt2+1, cur = 1
        issue_loads(Ag, Bg, (kt2 + 3) * BK, avB, bvB);
        compute_tile(&As[1][0], &Bs[1][0], wm, wn, lane15, quad, acc);
        convert_store(&As[0][0], &Bs[0][0], srow, scol, avA, bvA);  // tile kt2+2
        lds_barrier();
    }

    // ---- tail: kt = NKT-2 (cur=0) then kt = NKT-1 (cur=1), no more issues ----
    compute_tile(&As[0][0], &Bs[0][0], wm, wn, lane15, quad, acc);
    convert_store(&As[1][0], &Bs[1][0], srow, scol, avB, bvB);      // tile NKT-1
    lds_barrier();
    compute_tile(&As[1][0], &Bs[1][0], wm, wn, lane15, quad, acc);

    // epilogue: C/D layout m = quad*4 + reg, n = lane&15
    const float* bp = bias + (size_t)p * DOUT;
    float bj[4];
    #pragma unroll
    for (int j = 0; j < 4; ++j)
        bj[j] = bp[n_base + wn * 64 + j * 16 + lane15];

    #pragma unroll
    for (int i = 0; i < 4; ++i) {
        #pragma unroll
        for (int r = 0; r < 4; ++r) {
            const int m = m_base + wm * 64 + i * 16 + quad * 4 + r;
            float* orow = out + (size_t)m * (POP * DOUT) + (size_t)p * DOUT;
            #pragma unroll
            for (int j = 0; j < 4; ++j) {
                const int n = n_base + wn * 64 + j * 16 + lane15;
                orow[n] = acc[i][j][r] + bj[j];
            }
        }
    }
}

extern "C" void kernel_launch(void* const* d_in, const int* in_sizes, int n_in,
                              void* d_out, int out_size, void* d_ws, size_t ws_size,
                              hipStream_t stream) {
    const float* x    = (const float*)d_in[0];
    const float* w    = (const float*)d_in[1];
    const float* bias = (const float*)d_in[2];
    float* out        = (float*)d_out;

    const int grid = POP * (BATCH / BM) * (DOUT / BN);  // 128 * 2 * 8 = 2048
    pop_linear_kernel<<<grid, 256, 0, stream>>>(x, w, bias, out);
}